// Round 10
// baseline (2595.618 us; speedup 1.0000x reference)
//
#include <hip/hip_runtime.h>
#include <math.h>

#define AA 32
#define BB 2048
#define BP1 2049
#define CC 256
#define NROWS (AA * BP1)          // 65568
#define NBLK 3
#define FFN 1024

typedef unsigned int uint;
typedef unsigned short ushort_t;
typedef __attribute__((ext_vector_type(4))) float f32x4;
typedef __attribute__((ext_vector_type(8))) short short8;

// epilogue flag bits for mm_k (wave-uniform runtime flags)
#define F_ROWMAP 2
#define F_BIAS2D 4
#define F_BIAS1D 8
#define F_GELU   16
#define F_RESID  32
#define F_OUTB16 64
#define F_QKV    128

__device__ __forceinline__ float bf2f(ushort_t u) {
    return __uint_as_float(((uint)u) << 16);
}
__device__ __forceinline__ ushort_t f2b(float x) {   // fp32 -> bf16 RNE
    uint u = __float_as_uint(x);
    u += 0x7fff + ((u >> 16) & 1);
    return (ushort_t)(u >> 16);
}

// chunk-rotation swizzle: within each 32-col group, 16B chunk c -> (c + (row>>1)) & 3
__device__ __forceinline__ int swzcol(int col, int row) {
    int cp = (((col >> 3) & 3) + (row >> 1)) & 3;
    return (col & ~24) | (cp << 3);
}

// global -> LDS direct 16B load
typedef const uint __attribute__((address_space(1)))* gas_t;
typedef uint __attribute__((address_space(3)))* las_t;
__device__ __forceinline__ void gload16(const ushort_t* g, const short* l) {
    __builtin_amdgcn_global_load_lds(
        reinterpret_cast<gas_t>(reinterpret_cast<uintptr_t>(g)),
        reinterpret_cast<las_t>(static_cast<uint>(reinterpret_cast<uintptr_t>(l))),
        16, 0, 0);
}

// ---------------- fp32 -> two bf16 planes (hi, lo), chunk-swizzled ----------------
__global__ __launch_bounds__(256) void pack2_k(const float* __restrict__ src,
                                               ushort_t* __restrict__ dh,
                                               ushort_t* __restrict__ dl, int n, int kshift) {
    int i = blockIdx.x * 256 + threadIdx.x;
    if (i < n) {
        float v = src[i];
        ushort_t h = f2b(v);
        int row = i >> kshift;
        int di = (i & ~24) | (((((i >> 3) & 3) + (row >> 1)) & 3) << 3);
        dh[di] = h;
        dl[di] = f2b(v - bf2f(h));
    }
}

// ---------------- row 0 of each batch: cls + bias ----------------
__global__ __launch_bounds__(256) void row0_k(float* __restrict__ out,
                                              const float* __restrict__ cls,
                                              const float* __restrict__ bias) {
    int i = blockIdx.x, t = threadIdx.x;
    size_t o = (size_t)i * BP1 * CC + t;
    out[o] = cls[i * CC + t] + bias[o];
}

// ---------------- layernorm f32 -> split planes (swizzled) ----------------
__global__ __launch_bounds__(256) void ln_k(const float* __restrict__ in,
                                            ushort_t* __restrict__ zh, ushort_t* __restrict__ zl,
                                            const float* __restrict__ g, const float* __restrict__ b) {
    int row = blockIdx.x * 4 + (threadIdx.x >> 6);
    int lane = threadIdx.x & 63;
    const float4 v = *reinterpret_cast<const float4*>(in + (size_t)row * CC + lane * 4);
    float s = v.x + v.y + v.z + v.w;
    float sq = v.x * v.x + v.y * v.y + v.z * v.z + v.w * v.w;
    #pragma unroll
    for (int m = 1; m < 64; m <<= 1) { s += __shfl_xor(s, m); sq += __shfl_xor(sq, m); }
    float mu = s * (1.0f / CC);
    float var = sq * (1.0f / CC) - mu * mu;
    float rs = rsqrtf(var + 1e-5f);
    const float4 gg = *reinterpret_cast<const float4*>(g + lane * 4);
    const float4 bb = *reinterpret_cast<const float4*>(b + lane * 4);
    float o[4];
    o[0] = (v.x - mu) * rs * gg.x + bb.x;
    o[1] = (v.y - mu) * rs * gg.y + bb.y;
    o[2] = (v.z - mu) * rs * gg.z + bb.z;
    o[3] = (v.w - mu) * rs * gg.w + bb.w;
    ushort4 hs, ls;
    hs.x = f2b(o[0]); ls.x = f2b(o[0] - bf2f(hs.x));
    hs.y = f2b(o[1]); ls.y = f2b(o[1] - bf2f(hs.y));
    hs.z = f2b(o[2]); ls.z = f2b(o[2] - bf2f(hs.z));
    hs.w = f2b(o[3]); ls.w = f2b(o[3] - bf2f(hs.w));
    size_t base = (size_t)row * CC + swzcol(lane * 4, row);
    *reinterpret_cast<ushort4*>(zh + base) = hs;
    *reinterpret_cast<ushort4*>(zl + base) = ls;
}

// ---------------- rsa from bf16 qk buffer (unswizzled): rsa[r][h] = (q.k)/sqrt(32) ----------------
__global__ __launch_bounds__(256) void rsa2_k(const ushort_t* __restrict__ qk,
                                              float* __restrict__ rsa) {
    int row = blockIdx.x * 4 + (threadIdx.x >> 6);
    int l = threadIdx.x & 63;
    const ushort4 qa = *reinterpret_cast<const ushort4*>(qk + (size_t)row * 512 + l * 4);
    const ushort4 ka = *reinterpret_cast<const ushort4*>(qk + (size_t)row * 512 + 256 + l * 4);
    float p = bf2f(qa.x) * bf2f(ka.x) + bf2f(qa.y) * bf2f(ka.y)
            + bf2f(qa.z) * bf2f(ka.z) + bf2f(qa.w) * bf2f(ka.w);
    p += __shfl_xor(p, 1); p += __shfl_xor(p, 2); p += __shfl_xor(p, 4);
    if ((l & 7) == 0) rsa[(size_t)row * 8 + (l >> 3)] = p * 0.17677669529663689f;
}

// ---------------- cumsum pass 1: per-chunk totals of rsa*v (read-only) ----------------
__global__ __launch_bounds__(256) void cumsum1_k(const float* __restrict__ v,
                                                 const float* __restrict__ rsa,
                                                 float* __restrict__ tot) {
    int bi = blockIdx.x >> 3, ch = blockIdx.x & 7, c = threadIdx.x;
    int h = c >> 5;
    size_t row0 = (size_t)bi * BP1 + ch * 256;
    float s = 0.f;
    for (int j = 0; j < 256; ++j)
        s += v[(row0 + j) * CC + c] * rsa[(row0 + j) * 8 + h];
    tot[((size_t)bi * 8 + ch) * CC + c] = s;
}

// ---------------- cumsum pass 2: scan rsa*v + offset -> split planes (swizzled) ----------------
__global__ __launch_bounds__(256) void cumsum2_k(const float* __restrict__ v,
                                                 const float* __restrict__ rsa,
                                                 const float* __restrict__ tot,
                                                 ushort_t* __restrict__ ph,
                                                 ushort_t* __restrict__ pl) {
    int bi = blockIdx.x / 9, ch = blockIdx.x - bi * 9, c = threadIdx.x;
    int h = c >> 5;
    if (ch == 8) {
        size_t row = (size_t)bi * BP1 + BB;
        float val = v[row * CC + c] * rsa[row * 8 + h];
        ushort_t hh = f2b(val);
        size_t o = row * CC + swzcol(c, (int)(row & 2047) | (int)(row & ~2047ULL));
        // note: swz uses full row index; compute directly:
        o = row * CC + swzcol(c, (int)row);
        ph[o] = hh; pl[o] = f2b(val - bf2f(hh));
        return;
    }
    float s = 0.f;
    for (int q = 0; q < ch; ++q) s += tot[((size_t)bi * 8 + q) * CC + c];
    size_t row0 = (size_t)bi * BP1 + ch * 256;
    for (int j = 0; j < 256; ++j) {
        size_t row = row0 + j;
        s += v[row * CC + c] * rsa[row * 8 + h];
        ushort_t hh = f2b(s);
        size_t o = row * CC + swzcol(c, (int)row);
        ph[o] = hh;
        pl[o] = f2b(s - bf2f(hh));
    }
}

// ---------------- split-bf16 MFMA GEMM, swizzled plane operands + global_load_lds ----------------
template<int ALO>
__global__ __launch_bounds__(256) void mm_k(const ushort_t* __restrict__ Ah_g,
                                            const ushort_t* __restrict__ Al_g,
                                            const ushort_t* __restrict__ Bh_g,
                                            const ushort_t* __restrict__ Bl_g,
                                            void* __restrict__ Op,
                                            void* __restrict__ Op2,
                                            const float* __restrict__ bias,
                                            int M, int K, int NC, int NT, int flags) {
    __shared__ __align__(16) short As_h[4096];
    __shared__ __align__(16) short As_l[4096];
    __shared__ __align__(16) short Bs_h[4096];
    __shared__ __align__(16) short Bs_l[4096];
    const int t = threadIdx.x;

    // XCD-bijective block swizzle (m204)
    const int nwg = gridDim.x;
    const int q8 = nwg >> 3, r8 = nwg & 7;
    const int xcd = blockIdx.x & 7, ii = blockIdx.x >> 3;
    const int wgid = (xcd < r8 ? xcd * (q8 + 1) : r8 * (q8 + 1) + (xcd - r8) * q8) + ii;
    const int nt = wgid % NT, mt = wgid / NT;
    const int n0 = nt * 128, m0 = mt * 128;

    const int wid = t >> 6, l = t & 63;
    const int wr = wid >> 1, wc = wid & 1;

    const int ch0 = wid, ch1 = wid + 4;
    const int sr0 = ch0 * 16 + (l >> 2);
    const int sr1 = ch1 * 16 + (l >> 2);
    const int sc  = (l & 3) * 8;
    int ga0 = m0 + sr0; if (ga0 >= M) ga0 = M - 1;
    int ga1 = m0 + sr1; if (ga1 >= M) ga1 = M - 1;
    const int gb0 = n0 + sr0, gb1 = n0 + sr1;

    f32x4 acc[4][4];
    #pragma unroll
    for (int i = 0; i < 4; ++i)
        #pragma unroll
        for (int j = 0; j < 4; ++j) acc[i][j] = (f32x4)(0.0f);

    for (int k0 = 0; k0 < K; k0 += 32) {
        gload16(Ah_g + (size_t)ga0 * K + k0 + sc, &As_h[ch0 * 512]);
        gload16(Ah_g + (size_t)ga1 * K + k0 + sc, &As_h[ch1 * 512]);
        if (ALO) {
            gload16(Al_g + (size_t)ga0 * K + k0 + sc, &As_l[ch0 * 512]);
            gload16(Al_g + (size_t)ga1 * K + k0 + sc, &As_l[ch1 * 512]);
        }
        gload16(Bh_g + (size_t)gb0 * K + k0 + sc, &Bs_h[ch0 * 512]);
        gload16(Bh_g + (size_t)gb1 * K + k0 + sc, &Bs_h[ch1 * 512]);
        gload16(Bl_g + (size_t)gb0 * K + k0 + sc, &Bs_l[ch0 * 512]);
        gload16(Bl_g + (size_t)gb1 * K + k0 + sc, &Bs_l[ch1 * 512]);
        __syncthreads();
        short8 ah[4], al[4], bh[4], bl[4];
        #pragma unroll
        for (int i = 0; i < 4; ++i) {
            int r = wr * 64 + i * 16 + (l & 15);
            int ro = r * 32 + ((((l >> 4) + (r >> 1)) & 3) << 3);
            ah[i] = *reinterpret_cast<const short8*>(&As_h[ro]);
            if (ALO) al[i] = *reinterpret_cast<const short8*>(&As_l[ro]);
        }
        #pragma unroll
        for (int j = 0; j < 4; ++j) {
            int r = wc * 64 + j * 16 + (l & 15);
            int ro = r * 32 + ((((l >> 4) + (r >> 1)) & 3) << 3);
            bh[j] = *reinterpret_cast<const short8*>(&Bs_h[ro]);
            bl[j] = *reinterpret_cast<const short8*>(&Bs_l[ro]);
        }
        #pragma unroll
        for (int i = 0; i < 4; ++i)
            #pragma unroll
            for (int j = 0; j < 4; ++j) {
                acc[i][j] = __builtin_amdgcn_mfma_f32_16x16x32_bf16(ah[i], bh[j], acc[i][j], 0, 0, 0);
                acc[i][j] = __builtin_amdgcn_mfma_f32_16x16x32_bf16(ah[i], bl[j], acc[i][j], 0, 0, 0);
                if (ALO)
                    acc[i][j] = __builtin_amdgcn_mfma_f32_16x16x32_bf16(al[i], bh[j], acc[i][j], 0, 0, 0);
            }
        __syncthreads();
    }

    // ---- epilogue ----
    #pragma unroll
    for (int i = 0; i < 4; ++i)
        #pragma unroll
        for (int j = 0; j < 4; ++j) {
            int colb = n0 + wc * 64 + j * 16 + (l & 15);
            #pragma unroll
            for (int r = 0; r < 4; ++r) {
                int row = m0 + wr * 64 + i * 16 + (l >> 4) * 4 + r;
                if (row >= M) continue;
                float v = acc[i][j][r];
                if (flags & F_QKV) {
                    if (colb < 512)
                        reinterpret_cast<ushort_t*>(Op)[(size_t)row * 512 + colb] = f2b(v);
                    else
                        reinterpret_cast<float*>(Op2)[(size_t)row * 256 + (colb - 512)] = v;
                    continue;
                }
                size_t g = (flags & F_ROWMAP) ? ((size_t)(row >> 11) * BP1 + 1 + (row & 2047))
                                             : (size_t)row;
                if (flags & F_BIAS1D) v += bias[colb];
                if (flags & F_BIAS2D) v += bias[g * (size_t)NC + colb];
                if (flags & F_GELU) {   // tanh-form GELU: v * sigmoid(1.5958v + 0.07135v^3)
                    float z = v * (1.595769122f + 0.071354816f * v * v);
                    v = v / (1.0f + __expf(-z));
                }
                if (flags & F_OUTB16) {
                    // hbuf is a GEMM A-operand -> store swizzled
                    size_t oi = g * (size_t)NC + swzcol(colb, row);
                    reinterpret_cast<ushort_t*>(Op)[oi] = f2b(v);
                } else {
                    size_t oi = g * (size_t)NC + colb;
                    float* O = reinterpret_cast<float*>(Op);
                    if (flags & F_RESID) v += O[oi];
                    O[oi] = v;
                }
            }
        }
}

// ---------------- launch ----------------
extern "C" void kernel_launch(void* const* d_in, const int* in_sizes, int n_in,
                              void* d_out, int out_size, void* d_ws, size_t ws_size,
                              hipStream_t stream) {
    const float* x      = (const float*)d_in[0];
    const float* weight = (const float*)d_in[1];
    const float* bias   = (const float*)d_in[2];
    const float* cls    = (const float*)d_in[3];
    const float* Wqkv   = (const float*)d_in[4];
    const float* Wo     = (const float*)d_in[5];
    const float* ln1_g  = (const float*)d_in[6];
    const float* ln1_b  = (const float*)d_in[7];
    const float* ln2_g  = (const float*)d_in[8];
    const float* ln2_b  = (const float*)d_in[9];
    const float* fc1_w  = (const float*)d_in[10];
    const float* fc1_b  = (const float*)d_in[11];
    const float* fc2_w  = (const float*)d_in[12];
    const float* fc2_b  = (const float*)d_in[13];
    float* out = (float*)d_out;

    // ---- workspace (high-water 209,290,240 B — proven rounds 7/8/9) ----
    char* ws = (char*)d_ws;
    ushort_t* zh    = (ushort_t*)(ws + 0);
    ushort_t* zl    = (ushort_t*)(ws + 33570816);
    float*    vbuf  = (float*)(ws + 67141632);
    ushort_t* qkbuf = (ushort_t*)(ws + 134283264);
    ushort_t* imh   = (ushort_t*)(ws + 134283264);             // overlays qkbuf
    ushort_t* iml   = (ushort_t*)(ws + 167854080);
    ushort_t* hbuf  = (ushort_t*)(ws + 67141632);              // spans R1+R2
    float*    rsa   = (float*)(ws + 201424896);
    float*    tot   = (float*)(ws + 203523072);
    ushort_t* wp    = (ushort_t*)(ws + 203785216);

    ushort_t* w_h    = wp;                 // weight  65,536
    ushort_t* w_l    = wp + 65536;
    ushort_t* wqkv_h = wp + 131072;        // Wqkv   589,824
    ushort_t* wqkv_l = wp + 720896;
    ushort_t* wo_h   = wp + 1310720;       // Wo     196,608
    ushort_t* wo_l   = wp + 1507328;
    ushort_t* fc1_h  = wp + 1703936;       // fc1    262,144
    ushort_t* fc1_l  = wp + 1966080;
    ushort_t* fc2_h  = wp + 2228224;       // fc2    262,144
    ushort_t* fc2_l  = wp + 2490368;       // end 2,752,512 -> 209,290,240 B

    pack2_k<<<256,  256, 0, stream>>>(weight, w_h,    w_l,    65536,  8);
    pack2_k<<<2304, 256, 0, stream>>>(Wqkv,   wqkv_h, wqkv_l, 589824, 8);
    pack2_k<<<768,  256, 0, stream>>>(Wo,     wo_h,   wo_l,   196608, 8);
    pack2_k<<<1024, 256, 0, stream>>>(fc1_w,  fc1_h,  fc1_l,  262144, 8);
    pack2_k<<<1024, 256, 0, stream>>>(fc2_w,  fc2_h,  fc2_l,  262144, 10);
    pack2_k<<<65536, 256, 0, stream>>>(x, zh, zl, AA * BB * CC, 8);

    row0_k<<<AA, 256, 0, stream>>>(out, cls, bias);
    mm_k<1><<<1024, 256, 0, stream>>>(zh, zl, w_h, w_l, out, nullptr, bias,
                                      AA * BB, CC, CC, 2, F_ROWMAP | F_BIAS2D);

    const int MT = (NROWS + 127) / 128;   // 513
    for (int a = 0; a < NBLK; ++a) {
        const size_t aw = (size_t)a * 196608;   // per-layer Wqkv stride (3*8*32*256)
        ln_k<<<NROWS / 4, 256, 0, stream>>>(out, zh, zl, ln1_g, ln1_b);
        mm_k<1><<<6 * MT, 256, 0, stream>>>(zh, zl, wqkv_h + aw, wqkv_l + aw,
                                            qkbuf, vbuf, nullptr,
                                            NROWS, CC, 768, 6, F_QKV);
        rsa2_k<<<NROWS / 4, 256, 0, stream>>>(qkbuf, rsa);
        cumsum1_k<<<256, 256, 0, stream>>>(vbuf, rsa, tot);
        cumsum2_k<<<288, 256, 0, stream>>>(vbuf, rsa, tot, imh, iml);  // qkbuf dead
        mm_k<1><<<2 * MT, 256, 0, stream>>>(imh, iml, wo_h + (size_t)a * 65536,
                                            wo_l + (size_t)a * 65536, out, nullptr, nullptr,
                                            NROWS, CC, CC, 2, F_RESID);
        ln_k<<<NROWS / 4, 256, 0, stream>>>(out, zh, zl, ln2_g, ln2_b);
        mm_k<1><<<8 * MT, 256, 0, stream>>>(zh, zl, fc1_h, fc1_l, hbuf, nullptr, fc1_b,
                                            NROWS, CC, FFN, 8, F_BIAS1D | F_GELU | F_OUTB16);
        mm_k<0><<<2 * MT, 256, 0, stream>>>(hbuf, nullptr, fc2_h, fc2_l, out, nullptr, fc2_b,
                                            NROWS, FFN, CC, 2, F_BIAS1D | F_RESID);
    }
}

// Round 11
// 2203.331 us; speedup vs baseline: 1.1780x; 1.1780x over previous
//
#include <hip/hip_runtime.h>
#include <math.h>

#define AA 32
#define BB 2048
#define BP1 2049
#define CC 256
#define NROWS (AA * BP1)          // 65568
#define NBLK 3
#define FFN 1024

typedef unsigned int uint;
typedef unsigned short ushort_t;
typedef __attribute__((ext_vector_type(4))) float f32x4;
typedef __attribute__((ext_vector_type(8))) short short8;

// epilogue flag bits for mm_k (wave-uniform runtime flags)
#define F_ROWMAP 2
#define F_BIAS2D 4
#define F_BIAS1D 8
#define F_GELU   16
#define F_RESID  32
#define F_OUTB16 64
#define F_QKV    128

__device__ __forceinline__ float bf2f(ushort_t u) {
    return __uint_as_float(((uint)u) << 16);
}
__device__ __forceinline__ ushort_t f2b(float x) {   // fp32 -> bf16 RNE
    uint u = __float_as_uint(x);
    u += 0x7fff + ((u >> 16) & 1);
    return (ushort_t)(u >> 16);
}

// global -> LDS direct 16B load
typedef const uint __attribute__((address_space(1)))* gas_t;
typedef uint __attribute__((address_space(3)))* las_t;
__device__ __forceinline__ void gload16(const ushort_t* g, const short* l) {
    __builtin_amdgcn_global_load_lds(
        reinterpret_cast<gas_t>(reinterpret_cast<uintptr_t>(g)),
        reinterpret_cast<las_t>(static_cast<uint>(reinterpret_cast<uintptr_t>(l))),
        16, 0, 0);
}

// ---------------- fp32 -> two bf16 planes (hi, lo) ----------------
__global__ __launch_bounds__(256) void pack2_k(const float* __restrict__ src,
                                               ushort_t* __restrict__ dh,
                                               ushort_t* __restrict__ dl, int n) {
    int i = blockIdx.x * 256 + threadIdx.x;
    if (i < n) {
        float v = src[i];
        ushort_t h = f2b(v);
        dh[i] = h;
        dl[i] = f2b(v - bf2f(h));
    }
}

// ---------------- row 0 of each batch: cls + bias ----------------
__global__ __launch_bounds__(256) void row0_k(float* __restrict__ out,
                                              const float* __restrict__ cls,
                                              const float* __restrict__ bias) {
    int i = blockIdx.x, t = threadIdx.x;
    size_t o = (size_t)i * BP1 * CC + t;
    out[o] = cls[i * CC + t] + bias[o];
}

// ---------------- layernorm f32 -> split planes ----------------
__global__ __launch_bounds__(256) void ln_k(const float* __restrict__ in,
                                            ushort_t* __restrict__ zh, ushort_t* __restrict__ zl,
                                            const float* __restrict__ g, const float* __restrict__ b) {
    int row = blockIdx.x * 4 + (threadIdx.x >> 6);
    int lane = threadIdx.x & 63;
    const float4 v = *reinterpret_cast<const float4*>(in + (size_t)row * CC + lane * 4);
    float s = v.x + v.y + v.z + v.w;
    float sq = v.x * v.x + v.y * v.y + v.z * v.z + v.w * v.w;
    #pragma unroll
    for (int m = 1; m < 64; m <<= 1) { s += __shfl_xor(s, m); sq += __shfl_xor(sq, m); }
    float mu = s * (1.0f / CC);
    float var = sq * (1.0f / CC) - mu * mu;
    float rs = rsqrtf(var + 1e-5f);
    const float4 gg = *reinterpret_cast<const float4*>(g + lane * 4);
    const float4 bb = *reinterpret_cast<const float4*>(b + lane * 4);
    float o[4];
    o[0] = (v.x - mu) * rs * gg.x + bb.x;
    o[1] = (v.y - mu) * rs * gg.y + bb.y;
    o[2] = (v.z - mu) * rs * gg.z + bb.z;
    o[3] = (v.w - mu) * rs * gg.w + bb.w;
    ushort4 hs, ls;
    hs.x = f2b(o[0]); ls.x = f2b(o[0] - bf2f(hs.x));
    hs.y = f2b(o[1]); ls.y = f2b(o[1] - bf2f(hs.y));
    hs.z = f2b(o[2]); ls.z = f2b(o[2] - bf2f(hs.z));
    hs.w = f2b(o[3]); ls.w = f2b(o[3] - bf2f(hs.w));
    size_t base = (size_t)row * CC + lane * 4;
    *reinterpret_cast<ushort4*>(zh + base) = hs;
    *reinterpret_cast<ushort4*>(zl + base) = ls;
}

// ---------------- rsa from bf16 qk buffer: rsa[r][h] = (q.k)/sqrt(32) ----------------
__global__ __launch_bounds__(256) void rsa2_k(const ushort_t* __restrict__ qk,
                                              float* __restrict__ rsa) {
    int row = blockIdx.x * 4 + (threadIdx.x >> 6);
    int l = threadIdx.x & 63;
    const ushort4 qa = *reinterpret_cast<const ushort4*>(qk + (size_t)row * 512 + l * 4);
    const ushort4 ka = *reinterpret_cast<const ushort4*>(qk + (size_t)row * 512 + 256 + l * 4);
    float p = bf2f(qa.x) * bf2f(ka.x) + bf2f(qa.y) * bf2f(ka.y)
            + bf2f(qa.z) * bf2f(ka.z) + bf2f(qa.w) * bf2f(ka.w);
    p += __shfl_xor(p, 1); p += __shfl_xor(p, 2); p += __shfl_xor(p, 4);
    if ((l & 7) == 0) rsa[(size_t)row * 8 + (l >> 3)] = p * 0.17677669529663689f;
}

// ---------------- cumsum pass 1: per-chunk totals of rsa*v (read-only) ----------------
__global__ __launch_bounds__(256) void cumsum1_k(const float* __restrict__ v,
                                                 const float* __restrict__ rsa,
                                                 float* __restrict__ tot) {
    int bi = blockIdx.x >> 3, ch = blockIdx.x & 7, c = threadIdx.x;
    int h = c >> 5;
    size_t row0 = (size_t)bi * BP1 + ch * 256;
    float s = 0.f;
    for (int j = 0; j < 256; ++j)
        s += v[(row0 + j) * CC + c] * rsa[(row0 + j) * 8 + h];
    tot[((size_t)bi * 8 + ch) * CC + c] = s;
}

// ---------------- cumsum pass 2: scan rsa*v + offset -> split planes ----------------
__global__ __launch_bounds__(256) void cumsum2_k(const float* __restrict__ v,
                                                 const float* __restrict__ rsa,
                                                 const float* __restrict__ tot,
                                                 ushort_t* __restrict__ ph,
                                                 ushort_t* __restrict__ pl) {
    int bi = blockIdx.x / 9, ch = blockIdx.x - bi * 9, c = threadIdx.x;
    int h = c >> 5;
    if (ch == 8) {   // row BB (untouched by cumsum): scale + split-pack
        size_t row = (size_t)bi * BP1 + BB;
        float val = v[row * CC + c] * rsa[row * 8 + h];
        ushort_t hh = f2b(val);
        ph[row * CC + c] = hh; pl[row * CC + c] = f2b(val - bf2f(hh));
        return;
    }
    float s = 0.f;
    for (int q = 0; q < ch; ++q) s += tot[((size_t)bi * 8 + q) * CC + c];
    size_t row0 = (size_t)bi * BP1 + ch * 256;
    for (int j = 0; j < 256; ++j) {
        size_t row = row0 + j;
        s += v[row * CC + c] * rsa[row * 8 + h];
        ushort_t hh = f2b(s);
        ph[row * CC + c] = hh;
        pl[row * CC + c] = f2b(s - bf2f(hh));
    }
}

// ---------------- split-bf16 MFMA GEMM, dbuf LDS + counted-vmcnt pipeline ----------------
// Out(MxN) = A(MxK) * W(NxK)^T ; 1-D grid = NT*MT, XCD-bijective swizzle.
template<int ALO>
__global__ __launch_bounds__(256) void mm_k(const ushort_t* __restrict__ Ah_g,
                                            const ushort_t* __restrict__ Al_g,
                                            const ushort_t* __restrict__ Bh_g,
                                            const ushort_t* __restrict__ Bl_g,
                                            void* __restrict__ Op,
                                            void* __restrict__ Op2,
                                            const float* __restrict__ bias,
                                            int M, int K, int NC, int NT, int flags) {
    __shared__ __align__(16) short As_h[2][4096];
    __shared__ __align__(16) short As_l[2][4096];
    __shared__ __align__(16) short Bs_h[2][4096];
    __shared__ __align__(16) short Bs_l[2][4096];
    const int t = threadIdx.x;

    // XCD-bijective block swizzle (m204)
    const int nwg = gridDim.x;
    const int q8 = nwg >> 3, r8 = nwg & 7;
    const int xcd = blockIdx.x & 7, ii = blockIdx.x >> 3;
    const int wgid = (xcd < r8 ? xcd * (q8 + 1) : r8 * (q8 + 1) + (xcd - r8) * q8) + ii;
    const int nt_ = wgid % NT, mt = wgid / NT;
    const int n0 = nt_ * 128, m0 = mt * 128;

    const int wid = t >> 6, l = t & 63;
    const int wr = wid >> 1, wc = wid & 1;

    // staging geometry: wave w covers 1KB chunks (w) and (w+4); lane l -> row l>>2, col (l&3)*8
    const int ch0 = wid, ch1 = wid + 4;
    const int sr0 = ch0 * 16 + (l >> 2);
    const int sr1 = ch1 * 16 + (l >> 2);
    const int sc  = (l & 3) * 8;
    int ga0 = m0 + sr0; if (ga0 >= M) ga0 = M - 1;
    int ga1 = m0 + sr1; if (ga1 >= M) ga1 = M - 1;
    const int gb0 = n0 + sr0, gb1 = n0 + sr1;

    const ushort_t* a0 = Ah_g + (size_t)ga0 * K + sc;
    const ushort_t* a1 = Ah_g + (size_t)ga1 * K + sc;
    const ushort_t* a0l = Al_g + (size_t)ga0 * K + sc;
    const ushort_t* a1l = Al_g + (size_t)ga1 * K + sc;
    const ushort_t* b0h = Bh_g + (size_t)gb0 * K + sc;
    const ushort_t* b1h = Bh_g + (size_t)gb1 * K + sc;
    const ushort_t* b0l = Bl_g + (size_t)gb0 * K + sc;
    const ushort_t* b1l = Bl_g + (size_t)gb1 * K + sc;

    f32x4 acc[4][4];
    #pragma unroll
    for (int i = 0; i < 4; ++i)
        #pragma unroll
        for (int j = 0; j < 4; ++j) acc[i][j] = (f32x4)(0.0f);

    #define STAGE(buf, k0)                                                   \
        do {                                                                 \
            gload16(a0 + (k0), &As_h[buf][ch0 * 512]);                       \
            gload16(a1 + (k0), &As_h[buf][ch1 * 512]);                       \
            if (ALO) {                                                       \
                gload16(a0l + (k0), &As_l[buf][ch0 * 512]);                  \
                gload16(a1l + (k0), &As_l[buf][ch1 * 512]);                  \
            }                                                                \
            gload16(b0h + (k0), &Bs_h[buf][ch0 * 512]);                      \
            gload16(b1h + (k0), &Bs_h[buf][ch1 * 512]);                      \
            gload16(b0l + (k0), &Bs_l[buf][ch0 * 512]);                      \
            gload16(b1l + (k0), &Bs_l[buf][ch1 * 512]);                      \
        } while (0)

    const int ntile = K >> 5;
    STAGE(0, 0);                          // prologue: tile 0 -> buf 0

    for (int tt = 0; tt < ntile; ++tt) {
        const int cur = tt & 1;
        if (tt + 1 < ntile) {
            STAGE(cur ^ 1, (tt + 1) * 32);     // prefetch next tile
            if (ALO) asm volatile("s_waitcnt vmcnt(8)" ::: "memory");
            else     asm volatile("s_waitcnt vmcnt(6)" ::: "memory");
        } else {
            asm volatile("s_waitcnt vmcnt(0)" ::: "memory");
        }
        __builtin_amdgcn_s_barrier();          // cur tile visible to all waves
        __builtin_amdgcn_sched_barrier(0);

        short8 ah[4], al[4], bh[4], bl[4];
        #pragma unroll
        for (int i = 0; i < 4; ++i) {
            int ro = (wr * 64 + i * 16 + (l & 15)) * 32 + (l >> 4) * 8;
            ah[i] = *reinterpret_cast<const short8*>(&As_h[cur][ro]);
            if (ALO) al[i] = *reinterpret_cast<const short8*>(&As_l[cur][ro]);
        }
        #pragma unroll
        for (int j = 0; j < 4; ++j) {
            int ro = (wc * 64 + j * 16 + (l & 15)) * 32 + (l >> 4) * 8;
            bh[j] = *reinterpret_cast<const short8*>(&Bs_h[cur][ro]);
            bl[j] = *reinterpret_cast<const short8*>(&Bs_l[cur][ro]);
        }
        #pragma unroll
        for (int i = 0; i < 4; ++i)
            #pragma unroll
            for (int j = 0; j < 4; ++j) {
                acc[i][j] = __builtin_amdgcn_mfma_f32_16x16x32_bf16(ah[i], bh[j], acc[i][j], 0, 0, 0);
                acc[i][j] = __builtin_amdgcn_mfma_f32_16x16x32_bf16(ah[i], bl[j], acc[i][j], 0, 0, 0);
                if (ALO)
                    acc[i][j] = __builtin_amdgcn_mfma_f32_16x16x32_bf16(al[i], bh[j], acc[i][j], 0, 0, 0);
            }
        __builtin_amdgcn_s_barrier();          // all reads of cur done before overwrite
    }
    #undef STAGE

    // ---- epilogue ----
    #pragma unroll
    for (int i = 0; i < 4; ++i)
        #pragma unroll
        for (int j = 0; j < 4; ++j) {
            int colb = n0 + wc * 64 + j * 16 + (l & 15);
            #pragma unroll
            for (int r = 0; r < 4; ++r) {
                int row = m0 + wr * 64 + i * 16 + (l >> 4) * 4 + r;
                if (row >= M) continue;
                float v = acc[i][j][r];
                if (flags & F_QKV) {          // block-uniform by n-tile
                    if (colb < 512)
                        reinterpret_cast<ushort_t*>(Op)[(size_t)row * 512 + colb] = f2b(v);
                    else
                        reinterpret_cast<float*>(Op2)[(size_t)row * 256 + (colb - 512)] = v;
                    continue;
                }
                size_t g = (flags & F_ROWMAP) ? ((size_t)(row >> 11) * BP1 + 1 + (row & 2047))
                                             : (size_t)row;
                if (flags & F_BIAS1D) v += bias[colb];
                if (flags & F_BIAS2D) v += bias[g * (size_t)NC + colb];
                if (flags & F_GELU) {   // tanh-form GELU: v * sigmoid(1.5958v + 0.07135v^3)
                    float z = v * (1.595769122f + 0.071354816f * v * v);
                    v = v / (1.0f + __expf(-z));
                }
                size_t oi = g * (size_t)NC + colb;
                if (flags & F_OUTB16) {
                    reinterpret_cast<ushort_t*>(Op)[oi] = f2b(v);
                } else {
                    float* O = reinterpret_cast<float*>(Op);
                    if (flags & F_RESID) v += O[oi];
                    O[oi] = v;
                }
            }
        }
}

// ---------------- launch ----------------
extern "C" void kernel_launch(void* const* d_in, const int* in_sizes, int n_in,
                              void* d_out, int out_size, void* d_ws, size_t ws_size,
                              hipStream_t stream) {
    const float* x      = (const float*)d_in[0];
    const float* weight = (const float*)d_in[1];
    const float* bias   = (const float*)d_in[2];
    const float* cls    = (const float*)d_in[3];
    const float* Wqkv   = (const float*)d_in[4];
    const float* Wo     = (const float*)d_in[5];
    const float* ln1_g  = (const float*)d_in[6];
    const float* ln1_b  = (const float*)d_in[7];
    const float* ln2_g  = (const float*)d_in[8];
    const float* ln2_b  = (const float*)d_in[9];
    const float* fc1_w  = (const float*)d_in[10];
    const float* fc1_b  = (const float*)d_in[11];
    const float* fc2_w  = (const float*)d_in[12];
    const float* fc2_b  = (const float*)d_in[13];
    float* out = (float*)d_out;

    // ---- workspace (high-water 209,290,240 B — proven rounds 7-10) ----
    char* ws = (char*)d_ws;
    ushort_t* zh    = (ushort_t*)(ws + 0);
    ushort_t* zl    = (ushort_t*)(ws + 33570816);
    float*    vbuf  = (float*)(ws + 67141632);
    ushort_t* qkbuf = (ushort_t*)(ws + 134283264);
    ushort_t* imh   = (ushort_t*)(ws + 134283264);             // overlays qkbuf
    ushort_t* iml   = (ushort_t*)(ws + 167854080);
    ushort_t* hbuf  = (ushort_t*)(ws + 67141632);              // spans R1+R2
    float*    rsa   = (float*)(ws + 201424896);
    float*    tot   = (float*)(ws + 203523072);
    ushort_t* wp    = (ushort_t*)(ws + 203785216);

    ushort_t* w_h    = wp;                 // weight  65,536
    ushort_t* w_l    = wp + 65536;
    ushort_t* wqkv_h = wp + 131072;        // Wqkv   589,824
    ushort_t* wqkv_l = wp + 720896;
    ushort_t* wo_h   = wp + 1310720;       // Wo     196,608
    ushort_t* wo_l   = wp + 1507328;
    ushort_t* fc1_h  = wp + 1703936;       // fc1    262,144
    ushort_t* fc1_l  = wp + 1966080;
    ushort_t* fc2_h  = wp + 2228224;       // fc2    262,144
    ushort_t* fc2_l  = wp + 2490368;       // end 2,752,512 -> 209,290,240 B

    pack2_k<<<256,  256, 0, stream>>>(weight, w_h,    w_l,    65536);
    pack2_k<<<2304, 256, 0, stream>>>(Wqkv,   wqkv_h, wqkv_l, 589824);
    pack2_k<<<768,  256, 0, stream>>>(Wo,     wo_h,   wo_l,   196608);
    pack2_k<<<1024, 256, 0, stream>>>(fc1_w,  fc1_h,  fc1_l,  262144);
    pack2_k<<<1024, 256, 0, stream>>>(fc2_w,  fc2_h,  fc2_l,  262144);
    pack2_k<<<65536, 256, 0, stream>>>(x, zh, zl, AA * BB * CC);

    row0_k<<<AA, 256, 0, stream>>>(out, cls, bias);
    mm_k<1><<<1024, 256, 0, stream>>>(zh, zl, w_h, w_l, out, nullptr, bias,
                                      AA * BB, CC, CC, 2, F_ROWMAP | F_BIAS2D);

    const int MT = (NROWS + 127) / 128;   // 513
    for (int a = 0; a < NBLK; ++a) {
        const size_t aw = (size_t)a * 196608;   // per-layer Wqkv stride (3*8*32*256)
        ln_k<<<NROWS / 4, 256, 0, stream>>>(out, zh, zl, ln1_g, ln1_b);
        mm_k<1><<<6 * MT, 256, 0, stream>>>(zh, zl, wqkv_h + aw, wqkv_l + aw,
                                            qkbuf, vbuf, nullptr,
                                            NROWS, CC, 768, 6, F_QKV);
        rsa2_k<<<NROWS / 4, 256, 0, stream>>>(qkbuf, rsa);
        cumsum1_k<<<256, 256, 0, stream>>>(vbuf, rsa, tot);
        cumsum2_k<<<288, 256, 0, stream>>>(vbuf, rsa, tot, imh, iml);  // qkbuf dead
        mm_k<1><<<2 * MT, 256, 0, stream>>>(imh, iml, wo_h + (size_t)a * 65536,
                                            wo_l + (size_t)a * 65536, out, nullptr, nullptr,
                                            NROWS, CC, CC, 2, F_RESID);
        ln_k<<<NROWS / 4, 256, 0, stream>>>(out, zh, zl, ln2_g, ln2_b);
        mm_k<1><<<8 * MT, 256, 0, stream>>>(zh, zl, fc1_h, fc1_l, hbuf, nullptr, fc1_b,
                                            NROWS, CC, FFN, 8, F_BIAS1D | F_GELU | F_OUTB16);
        mm_k<0><<<2 * MT, 256, 0, stream>>>(hbuf, nullptr, fc2_h, fc2_l, out, nullptr, fc2_b,
                                            NROWS, FFN, CC, 2, F_BIAS1D | F_RESID);
    }
}